// Round 12
// baseline (208.027 us; speedup 1.0000x reference)
//
#include <hip/hip_runtime.h>
#include <stdint.h>

#define S_LEN 2048
#define D_EMBD 1024
#define N_HEADS 16
#define D_HEAD 64
#define B_SZ 4
#define M_TOT (B_SZ * S_LEN)   // 8192

typedef __bf16 bf16x8 __attribute__((ext_vector_type(8)));
typedef float f32x4 __attribute__((ext_vector_type(4)));
typedef float f32x16 __attribute__((ext_vector_type(16)));
typedef unsigned short u16x8 __attribute__((ext_vector_type(8)));
typedef unsigned int u32x4 __attribute__((ext_vector_type(4)));

__device__ __forceinline__ unsigned short f2bf(float f) {
  unsigned u = __builtin_bit_cast(unsigned, f);
  u += 0x7fffu + ((u >> 16) & 1u);
  return (unsigned short)(u >> 16);
}

__device__ __forceinline__ void async16(const void* g, void* l) {
  __builtin_amdgcn_global_load_lds(
      (const __attribute__((address_space(1))) void*)(uintptr_t)g,
      (__attribute__((address_space(3))) void*)(unsigned)(uintptr_t)l,
      16, 0, 0);
}

__device__ __forceinline__ f32x16 mfma32(bf16x8 a, bf16x8 b, f32x16 c) {
  return __builtin_amdgcn_mfma_f32_32x32x16_bf16(a, b, c, 0, 0, 0);
}

// All 4 weight matrices cast in one launch; dst buffers are contiguous.
__global__ __launch_bounds__(256) void cast_w4_kernel(
    const float* __restrict__ w0, const float* __restrict__ w1,
    const float* __restrict__ w2, const float* __restrict__ w3,
    unsigned short* __restrict__ out) {
  int i = blockIdx.x * 256 + threadIdx.x;        // 4 * 131072 threads
  int seg = i >> 17;
  int off = i & ((1 << 17) - 1);
  const float* src = (seg == 0) ? w0 : (seg == 1) ? w1 : (seg == 2) ? w2 : w3;
  size_t sb = (size_t)off * 8;
  float4 a = *(const float4*)(src + sb);
  float4 b = *(const float4*)(src + sb + 4);
  u16x8 r;
  r[0] = f2bf(a.x); r[1] = f2bf(a.y); r[2] = f2bf(a.z); r[3] = f2bf(a.w);
  r[4] = f2bf(b.x); r[5] = f2bf(b.y); r[6] = f2bf(b.z); r[7] = f2bf(b.w);
  *(u16x8*)(out + (size_t)i * 8) = r;
}

// C = oscale * (A[M,K] @ W[N,K]^T), 32x32x16 MFMA, XOR-swizzled LDS,
// double-buffered prefetch. AFP32: A fp32, cast fused into staging.
// (round-10 known-good config — reverted from the merged/via-LDS variant)
template <int MODE, bool AFP32>
__global__ __launch_bounds__(256) void gemm_bt(
    const void* __restrict__ Ain, const unsigned short* __restrict__ W,
    void* __restrict__ out, float oscale, int M, int N, int K) {
  const unsigned short* A16 = (const unsigned short*)Ain;
  const float* A32 = (const float*)Ain;
  __shared__ __align__(16) unsigned short As[2][128 * 64];
  __shared__ __align__(16) unsigned short Bs[2][128 * 64];
  const int tid = threadIdx.x;
  const int lane = tid & 63;
  const int w = tid >> 6;
  const int wr = w >> 1, wc = w & 1;
  const int l32 = lane & 31, hi = lane >> 5;

  const int nwg = gridDim.x * gridDim.y;
  const int bid = blockIdx.y * gridDim.x + blockIdx.x;
  const int wg = (bid & 7) * (nwg >> 3) + (bid >> 3);
  const int bm = wg >> 3;
  const int bn = wg & 7;

  f32x16 acc[2][2];
  #pragma unroll
  for (int i = 0; i < 2; i++)
    #pragma unroll
    for (int j = 0; j < 2; j++)
      #pragma unroll
      for (int r = 0; r < 16; r++) acc[i][j][r] = 0.f;

  const int srow = w * 32 + (lane >> 3);
  const int scolsw = ((lane & 7) ^ (lane >> 3)) * 8;   // elems

  f32x4 ar[4][2];   // fp32 A staging regs (AFP32 path)

  #define LOADA(k0)                                                            \
    do {                                                                       \
      _Pragma("unroll")                                                        \
      for (int p = 0; p < 4; ++p) {                                            \
        const float* srcp =                                                    \
            &A32[(size_t)(bm * 128 + srow + p * 8) * K + (k0) + scolsw];       \
        ar[p][0] = *(const f32x4*)srcp;                                        \
        ar[p][1] = *(const f32x4*)(srcp + 4);                                  \
      }                                                                        \
    } while (0)

  #define WRITEA(b)                                                            \
    do {                                                                       \
      _Pragma("unroll")                                                        \
      for (int p = 0; p < 4; ++p) {                                            \
        unsigned c0, c1, c2, c3;                                               \
        asm("v_cvt_pk_bf16_f32 %0, %1, %2" : "=v"(c0)                          \
            : "v"(ar[p][0][0]), "v"(ar[p][0][1]));                             \
        asm("v_cvt_pk_bf16_f32 %0, %1, %2" : "=v"(c1)                          \
            : "v"(ar[p][0][2]), "v"(ar[p][0][3]));                             \
        asm("v_cvt_pk_bf16_f32 %0, %1, %2" : "=v"(c2)                          \
            : "v"(ar[p][1][0]), "v"(ar[p][1][1]));                             \
        asm("v_cvt_pk_bf16_f32 %0, %1, %2" : "=v"(c3)                          \
            : "v"(ar[p][1][2]), "v"(ar[p][1][3]));                             \
        u32x4 pk = {c0, c1, c2, c3};                                           \
        *(u32x4*)((char*)As[b] + (w * 32 + p * 8) * 128 + lane * 16) = pk;     \
      }                                                                        \
    } while (0)

  #define STAGE_ASYNC(b, k0)                                                   \
    do {                                                                       \
      if constexpr (!AFP32) {                                                  \
        _Pragma("unroll")                                                      \
        for (int p = 0; p < 4; ++p)                                            \
          async16(&A16[(size_t)(bm * 128 + srow + p * 8) * K + (k0) + scolsw], \
                  &As[b][(w * 32 + p * 8) * 64]);                              \
      }                                                                        \
      _Pragma("unroll")                                                        \
      for (int p = 0; p < 4; ++p)                                              \
        async16(&W[(size_t)(bn * 128 + srow + p * 8) * K + (k0) + scolsw],     \
                &Bs[b][(w * 32 + p * 8) * 64]);                                \
    } while (0)

  if constexpr (AFP32) LOADA(0);
  STAGE_ASYNC(0, 0);
  if constexpr (AFP32) WRITEA(0);
  __syncthreads();

  int buf = 0;
  for (int k0 = 0; k0 < K; k0 += 64) {
    const bool more = (k0 + 64 < K);
    if (more) {
      if constexpr (AFP32) LOADA(k0 + 64);
      STAGE_ASYNC(buf ^ 1, k0 + 64);
    }
    #pragma unroll
    for (int ksub = 0; ksub < 4; ++ksub) {
      const int koff = ksub * 32 + hi * 16;   // byte offset in 128B row
      bf16x8 aA[2], bB[2];
      #pragma unroll
      for (int rb = 0; rb < 2; rb++) {
        int row = wr * 64 + rb * 32 + l32;
        aA[rb] = *(const bf16x8*)((const char*)As[buf] + row * 128 +
                                  (koff ^ ((l32 & 7) << 4)));
      }
      #pragma unroll
      for (int cb = 0; cb < 2; cb++) {
        int row = wc * 64 + cb * 32 + l32;
        bB[cb] = *(const bf16x8*)((const char*)Bs[buf] + row * 128 +
                                  (koff ^ ((l32 & 7) << 4)));
      }
      #pragma unroll
      for (int rb = 0; rb < 2; rb++)
        #pragma unroll
        for (int cb = 0; cb < 2; cb++)
          acc[rb][cb] = mfma32(aA[rb], bB[cb], acc[rb][cb]);
    }
    if (more) { if constexpr (AFP32) WRITEA(buf ^ 1); }
    __syncthreads();
    buf ^= 1;
  }
  #undef LOADA
  #undef WRITEA
  #undef STAGE_ASYNC

  #pragma unroll
  for (int rb = 0; rb < 2; rb++)
    #pragma unroll
    for (int cb = 0; cb < 2; cb++)
      #pragma unroll
      for (int r = 0; r < 16; r++) {
        int row = bm * 128 + wr * 64 + rb * 32 + (r & 3) + 8 * (r >> 2) + 4 * hi;
        int col = bn * 128 + wc * 64 + cb * 32 + l32;
        float v = acc[rb][cb][r] * oscale;
        if constexpr (MODE == 0) {
          size_t idx = ((size_t)((row >> 11) * N_HEADS + (col >> 6)) * S_LEN +
                        (row & (S_LEN - 1))) * D_HEAD + (col & (D_HEAD - 1));
          ((unsigned short*)out)[idx] = f2bf(v);
        } else if constexpr (MODE == 1) {
          ((float*)out)[(size_t)row * N + col] = v;
        } else {
          size_t idx = ((size_t)((row >> 11) * N_HEADS + (col >> 6)) * D_HEAD +
                        (col & (D_HEAD - 1))) * S_LEN + (row & (S_LEN - 1));
          ((unsigned short*)out)[idx] = f2bf(v);
        }
      }
}

// Flash attention: round-11 config (best measured) — 8 waves, K/V staged once
// per 256 q-rows, counted-vmcnt pipeline (K 3-deep, V 2-deep), tree max/sum.
__global__ __launch_bounds__(512, 4) void attn_kernel(
    const unsigned short* __restrict__ qh, const unsigned short* __restrict__ kh,
    const unsigned short* __restrict__ vt, unsigned short* __restrict__ xout) {
  __shared__ __align__(16) char smem[66560];
  const int tid = threadIdx.x;
  const int lane = tid & 63;
  const int w = tid >> 6;          // 0..7
  const int l32 = lane & 31;
  const int hi = lane >> 5;

  const int bid = blockIdx.x;                    // nwg = 512
  const int wg = (bid & 7) * 64 + (bid >> 3);    // XCD-chunked remap
  const int bh = wg >> 3;                        // 8 q-blocks per head
  const int qb = (wg & 7) * 256 + w * 32;

  const char* Kb = (const char*)kh + (size_t)bh * S_LEN * D_HEAD * 2;
  const char* Vb = (const char*)vt + (size_t)bh * D_HEAD * S_LEN * 2;
  const unsigned short* Q = qh + (size_t)bh * S_LEN * D_HEAD;

  bf16x8 qf[4];
  #pragma unroll
  for (int ks = 0; ks < 4; ks++)
    qf[ks] = *(const bf16x8*)&Q[(qb + l32) * 64 + ks * 16 + hi * 8];

  f32x16 o0, o1;
  #pragma unroll
  for (int r = 0; r < 16; r++) { o0[r] = 0.f; o1[r] = 0.f; }
  float m2 = -1e30f;
  float lsum = 0.f;

  #define STAGE_K(dstb, t)                                                     \
    do {                                                                       \
      int loff = tid * 16;                                                     \
      int krow = loff >> 7;                                                    \
      async16(Kb + (size_t)(t) * 8192 + (loff ^ ((krow & 7) << 4)),            \
              smem + (dstb) * 8192 + w * 1024);                                \
    } while (0)
  #define STAGE_V(dstb, t)                                                     \
    do {                                                                       \
      int loff = tid * 16;                                                     \
      int d = loff >> 7;                                                       \
      int colb = loff & 127;                                                   \
      async16(Vb + (size_t)d * 4096 + (t) * 128 + (colb ^ ((d & 7) << 4)),     \
              smem + 24576 + (dstb) * 8192 + w * 1024);                        \
    } while (0)

  auto compute = [&](const char* Ks, const char* Vs) __attribute__((always_inline)) {
    f32x16 s0, s1;
    #pragma unroll
    for (int r = 0; r < 16; r++) { s0[r] = 0.f; s1[r] = 0.f; }

    __builtin_amdgcn_s_setprio(1);
    #pragma unroll
    for (int ks = 0; ks < 4; ks++) {
      int row = l32;
      bf16x8 ka = *(const bf16x8*)(Ks + ((row * 128 + ks * 32 + hi * 16) ^
                                         ((row & 7) << 4)));
      s0 = mfma32(ka, qf[ks], s0);
    }
    #pragma unroll
    for (int ks = 0; ks < 4; ks++) {
      int row = 32 + l32;
      bf16x8 ka = *(const bf16x8*)(Ks + ((row * 128 + ks * 32 + hi * 16) ^
                                         ((row & 7) << 4)));
      s1 = mfma32(ka, qf[ks], s1);
    }
    __builtin_amdgcn_s_setprio(0);

    // online softmax (log2 domain; Q pre-scaled), defer-max THR=8, tree max
    float m8[8];
    #pragma unroll
    for (int t = 0; t < 8; t++)
      m8[t] = fmaxf(fmaxf(s0[2 * t], s0[2 * t + 1]),
                    fmaxf(s1[2 * t], s1[2 * t + 1]));
    float mx = fmaxf(fmaxf(fmaxf(m8[0], m8[1]), fmaxf(m8[2], m8[3])),
                     fmaxf(fmaxf(m8[4], m8[5]), fmaxf(m8[6], m8[7])));
    mx = fmaxf(mx, __shfl_xor(mx, 32));
    if (__any(mx > m2 + 8.0f)) {
      float mn = fmaxf(m2, mx);
      float sc = __builtin_amdgcn_exp2f(m2 - mn);
      lsum *= sc;
      #pragma unroll
      for (int r = 0; r < 16; r++) { o0[r] *= sc; o1[r] *= sc; }
      m2 = mn;
    }
    #pragma unroll
    for (int r = 0; r < 16; r++) {
      s0[r] = __builtin_amdgcn_exp2f(s0[r] - m2);   // bounded by 2^8
      s1[r] = __builtin_amdgcn_exp2f(s1[r] - m2);
    }
    float p8[8];
    #pragma unroll
    for (int t = 0; t < 8; t++)
      p8[t] = (s0[2 * t] + s0[2 * t + 1]) + (s1[2 * t] + s1[2 * t + 1]);
    lsum += ((p8[0] + p8[1]) + (p8[2] + p8[3])) +
            ((p8[4] + p8[5]) + (p8[6] + p8[7]));

    unsigned c[8], e[8];
    #pragma unroll
    for (int t = 0; t < 8; t++) {
      asm("v_cvt_pk_bf16_f32 %0, %1, %2"
          : "=v"(c[t]) : "v"(s0[2 * t]), "v"(s0[2 * t + 1]));
      asm("v_cvt_pk_bf16_f32 %0, %1, %2"
          : "=v"(e[t]) : "v"(s1[2 * t]), "v"(s1[2 * t + 1]));
    }
    asm("v_permlane32_swap_b32 %0, %1" : "+v"(c[0]), "+v"(c[2]));
    asm("v_permlane32_swap_b32 %0, %1" : "+v"(c[1]), "+v"(c[3]));
    asm("v_permlane32_swap_b32 %0, %1" : "+v"(c[4]), "+v"(c[6]));
    asm("v_permlane32_swap_b32 %0, %1" : "+v"(c[5]), "+v"(c[7]));
    asm("v_permlane32_swap_b32 %0, %1" : "+v"(e[0]), "+v"(e[2]));
    asm("v_permlane32_swap_b32 %0, %1" : "+v"(e[1]), "+v"(e[3]));
    asm("v_permlane32_swap_b32 %0, %1" : "+v"(e[4]), "+v"(e[6]));
    asm("v_permlane32_swap_b32 %0, %1" : "+v"(e[5]), "+v"(e[7]));
    u32x4 t0 = {c[0], c[1], c[2], c[3]};
    u32x4 t1 = {c[4], c[5], c[6], c[7]};
    u32x4 t2 = {e[0], e[1], e[2], e[3]};
    u32x4 t3 = {e[4], e[5], e[6], e[7]};
    bf16x8 pa0 = __builtin_bit_cast(bf16x8, t0);
    bf16x8 pa1 = __builtin_bit_cast(bf16x8, t1);
    bf16x8 pa2 = __builtin_bit_cast(bf16x8, t2);
    bf16x8 pa3 = __builtin_bit_cast(bf16x8, t3);

    __builtin_amdgcn_s_setprio(1);
    {
      int row = l32;
      bf16x8 va0 = *(const bf16x8*)(Vs + ((row * 128 + 0 * 32 + hi * 16) ^ ((row & 7) << 4)));
      bf16x8 va1 = *(const bf16x8*)(Vs + ((row * 128 + 1 * 32 + hi * 16) ^ ((row & 7) << 4)));
      bf16x8 va2 = *(const bf16x8*)(Vs + ((row * 128 + 2 * 32 + hi * 16) ^ ((row & 7) << 4)));
      bf16x8 va3 = *(const bf16x8*)(Vs + ((row * 128 + 3 * 32 + hi * 16) ^ ((row & 7) << 4)));
      o0 = mfma32(va0, pa0, o0);
      o0 = mfma32(va1, pa1, o0);
      o0 = mfma32(va2, pa2, o0);
      o0 = mfma32(va3, pa3, o0);
    }
    {
      int row = 32 + l32;
      bf16x8 va0 = *(const bf16x8*)(Vs + ((row * 128 + 0 * 32 + hi * 16) ^ ((row & 7) << 4)));
      bf16x8 va1 = *(const bf16x8*)(Vs + ((row * 128 + 1 * 32 + hi * 16) ^ ((row & 7) << 4)));
      bf16x8 va2 = *(const bf16x8*)(Vs + ((row * 128 + 2 * 32 + hi * 16) ^ ((row & 7) << 4)));
      bf16x8 va3 = *(const bf16x8*)(Vs + ((row * 128 + 3 * 32 + hi * 16) ^ ((row & 7) << 4)));
      o1 = mfma32(va0, pa0, o1);
      o1 = mfma32(va1, pa1, o1);
      o1 = mfma32(va2, pa2, o1);
      o1 = mfma32(va3, pa3, o1);
    }
    __builtin_amdgcn_s_setprio(0);
  };

  // Prologue: K0, V0, K1 in flight — issue order PINNED (vmcnt counts on it).
  STAGE_K(0, 0);
  __builtin_amdgcn_sched_barrier(0);
  STAGE_V(0, 0);
  __builtin_amdgcn_sched_barrier(0);
  STAGE_K(1, 1);
  __builtin_amdgcn_sched_barrier(0);

  int kcur = 0, vcur = 0;
  for (int t = 0; t < S_LEN / 64 - 1; ++t) {    // t = 0..30
    asm volatile("s_waitcnt vmcnt(1)" ::: "memory");
    __builtin_amdgcn_s_barrier();
    __builtin_amdgcn_sched_barrier(0);
    int vnx = vcur ^ 1;
    STAGE_V(vnx, t + 1);
    __builtin_amdgcn_sched_barrier(0);
    if (t < S_LEN / 64 - 2) {
      int knx = kcur + 2; if (knx >= 3) knx -= 3;
      STAGE_K(knx, t + 2);
    }
    __builtin_amdgcn_sched_barrier(0);
    compute(smem + kcur * 8192, smem + 24576 + vcur * 8192);
    kcur = (kcur == 2) ? 0 : kcur + 1;
    vcur = vnx;
  }
  asm volatile("s_waitcnt vmcnt(0)" ::: "memory");
  __builtin_amdgcn_s_barrier();
  __builtin_amdgcn_sched_barrier(0);
  compute(smem + kcur * 8192, smem + 24576 + vcur * 8192);   // t = 31

  #undef STAGE_K
  #undef STAGE_V

  lsum += __shfl_xor(lsum, 32);
  float inv = 1.0f / lsum;

  __syncthreads();   // all waves done with K/V LDS before O reuse
  float* O = (float*)(smem) + w * (32 * 65);
  #pragma unroll
  for (int r = 0; r < 16; r++) {
    int d = (r & 3) + 8 * (r >> 2) + 4 * hi;
    O[l32 * 65 + d] = o0[r] * inv;
    O[l32 * 65 + 32 + d] = o1[r] * inv;
  }
  __syncthreads();
  const int qr = lane >> 1;
  const int coff = (lane & 1) * 32;
  const int b = bh >> 4, h = bh & 15;
  unsigned short* dst =
      &xout[((size_t)(b * S_LEN) + qb + qr) * D_EMBD + h * 64 + coff];
  #pragma unroll
  for (int t = 0; t < 4; t++) {
    u16x8 rr;
    #pragma unroll
    for (int j = 0; j < 8; j++)
      rr[j] = f2bf(O[qr * 65 + coff + t * 8 + j]);
    *(u16x8*)(dst + t * 8) = rr;
  }
}

extern "C" void kernel_launch(void* const* d_in, const int* in_sizes, int n_in,
                              void* d_out, int out_size, void* d_ws, size_t ws_size,
                              hipStream_t stream) {
  const float* q   = (const float*)d_in[0];
  const float* k   = (const float*)d_in[1];
  const float* v   = (const float*)d_in[2];
  const float* wqf = (const float*)d_in[3];
  const float* wkf = (const float*)d_in[4];
  const float* wvf = (const float*)d_in[5];
  const float* wof = (const float*)d_in[6];

  char* ws = (char*)d_ws;
  unsigned short* qh = (unsigned short*)(ws + (16u << 20));        // 16 MB
  unsigned short* kh = (unsigned short*)(ws + (32u << 20));        // 16 MB
  unsigned short* vt = (unsigned short*)(ws + (48u << 20));        // 16 MB
  unsigned short* ax = (unsigned short*)(ws + (64u << 20));        // 16 MB
  unsigned short* wq = (unsigned short*)(ws + (80u << 20));        // 2 MB each, contiguous
  unsigned short* wk = wq + (1u << 20);
  unsigned short* wv = wk + (1u << 20);
  unsigned short* wo = wv + (1u << 20);

  const float QSCALE = 0.125f * 1.4426950408889634f;

  cast_w4_kernel<<<2048, 256, 0, stream>>>(wqf, wkf, wvf, wof, wq);

  dim3 gg(D_EMBD / 128, M_TOT / 128);  // (8, 64)

  gemm_bt<0, true><<<gg, 256, 0, stream>>>(q, wq, qh, QSCALE, M_TOT, D_EMBD, D_EMBD);
  gemm_bt<0, true><<<gg, 256, 0, stream>>>(k, wk, kh, 1.0f, M_TOT, D_EMBD, D_EMBD);
  gemm_bt<2, true><<<gg, 256, 0, stream>>>(v, wv, vt, 1.0f, M_TOT, D_EMBD, D_EMBD);

  attn_kernel<<<512, 512, 0, stream>>>(qh, kh, vt, ax);

  gemm_bt<1, false><<<gg, 256, 0, stream>>>(ax, wo, d_out, 1.0f, M_TOT, D_EMBD, D_EMBD);
}

// Round 13
// 207.622 us; speedup vs baseline: 1.0020x; 1.0020x over previous
//
#include <hip/hip_runtime.h>
#include <stdint.h>

#define S_LEN 2048
#define D_EMBD 1024
#define N_HEADS 16
#define D_HEAD 64
#define B_SZ 4
#define M_TOT (B_SZ * S_LEN)   // 8192

typedef __bf16 bf16x8 __attribute__((ext_vector_type(8)));
typedef float f32x4 __attribute__((ext_vector_type(4)));
typedef float f32x16 __attribute__((ext_vector_type(16)));
typedef unsigned short u16x8 __attribute__((ext_vector_type(8)));
typedef unsigned int u32x4 __attribute__((ext_vector_type(4)));

__device__ __forceinline__ unsigned short f2bf(float f) {
  unsigned u = __builtin_bit_cast(unsigned, f);
  u += 0x7fffu + ((u >> 16) & 1u);
  return (unsigned short)(u >> 16);
}

__device__ __forceinline__ void async16(const void* g, void* l) {
  __builtin_amdgcn_global_load_lds(
      (const __attribute__((address_space(1))) void*)(uintptr_t)g,
      (__attribute__((address_space(3))) void*)(unsigned)(uintptr_t)l,
      16, 0, 0);
}

__device__ __forceinline__ f32x16 mfma32(bf16x8 a, bf16x8 b, f32x16 c) {
  return __builtin_amdgcn_mfma_f32_32x32x16_bf16(a, b, c, 0, 0, 0);
}

// All 4 weight matrices cast in one launch; dst buffers are contiguous.
__global__ __launch_bounds__(256) void cast_w4_kernel(
    const float* __restrict__ w0, const float* __restrict__ w1,
    const float* __restrict__ w2, const float* __restrict__ w3,
    unsigned short* __restrict__ out) {
  int i = blockIdx.x * 256 + threadIdx.x;        // 4 * 131072 threads
  int seg = i >> 17;
  int off = i & ((1 << 17) - 1);
  const float* src = (seg == 0) ? w0 : (seg == 1) ? w1 : (seg == 2) ? w2 : w3;
  size_t sb = (size_t)off * 8;
  float4 a = *(const float4*)(src + sb);
  float4 b = *(const float4*)(src + sb + 4);
  u16x8 r;
  r[0] = f2bf(a.x); r[1] = f2bf(a.y); r[2] = f2bf(a.z); r[3] = f2bf(a.w);
  r[4] = f2bf(b.x); r[5] = f2bf(b.y); r[6] = f2bf(b.z); r[7] = f2bf(b.w);
  *(u16x8*)(out + (size_t)i * 8) = r;
}

// Merged Q/K/V projection GEMM: grid (8, 64, 3); z selects {A, W, out, mode}.
// SINGLE-BUFFERED LDS (m97-style 2-barrier loop): As 16KB + Bs 16KB main,
// 36KB epilogue region -> 36KB/block -> 4 blocks/CU (was 64KB -> 2/CU).
// A prefetch is register-double-buffered (LOADA early, WRITEA after barrier);
// only the B async16 drain is exposed, covered by 4 resident blocks (TLP).
__global__ __launch_bounds__(256) void proj_gemm(
    const float* __restrict__ Aq, const float* __restrict__ Ak,
    const float* __restrict__ Av, const unsigned short* __restrict__ Wbase,
    unsigned short* __restrict__ Obase, float qscale) {
  constexpr int K = 1024;
  __shared__ __align__(16) char smem[36864];
  // main: As @0 (16KB), Bs @16384 (16KB); epilogue wave tile @ w*9216
  const int tid = threadIdx.x;
  const int lane = tid & 63;
  const int w = tid >> 6;
  const int wr = w >> 1, wc = w & 1;
  const int l32 = lane & 31, hi = lane >> 5;

  const int z = blockIdx.z;
  const float* A32 = (z == 0) ? Aq : (z == 1) ? Ak : Av;
  const unsigned short* W = Wbase + ((size_t)z << 20);
  unsigned short* out = Obase + ((size_t)z << 23);
  const float oscale = (z == 0) ? qscale : 1.0f;
  const bool mode0 = (z < 2);

  const int nwg = gridDim.x * gridDim.y;   // 512 per slice
  const int bid = blockIdx.y * gridDim.x + blockIdx.x;
  const int wg = (bid & 7) * (nwg >> 3) + (bid >> 3);
  const int bm = wg >> 3;
  const int bn = wg & 7;

  f32x16 acc[2][2];
  #pragma unroll
  for (int i = 0; i < 2; i++)
    #pragma unroll
    for (int j = 0; j < 2; j++)
      #pragma unroll
      for (int r = 0; r < 16; r++) acc[i][j][r] = 0.f;

  const int srow = w * 32 + (lane >> 3);
  const int scolsw = ((lane & 7) ^ (lane >> 3)) * 8;   // elems

  f32x4 ar[4][2];   // fp32 A staging regs (register double-buffer)

  #define LOADA(k0)                                                            \
    do {                                                                       \
      _Pragma("unroll")                                                        \
      for (int p = 0; p < 4; ++p) {                                            \
        const float* srcp =                                                    \
            &A32[(size_t)(bm * 128 + srow + p * 8) * K + (k0) + scolsw];       \
        ar[p][0] = *(const f32x4*)srcp;                                        \
        ar[p][1] = *(const f32x4*)(srcp + 4);                                  \
      }                                                                        \
    } while (0)

  #define WRITEA()                                                             \
    do {                                                                       \
      _Pragma("unroll")                                                        \
      for (int p = 0; p < 4; ++p) {                                            \
        unsigned c0, c1, c2, c3;                                               \
        asm("v_cvt_pk_bf16_f32 %0, %1, %2" : "=v"(c0)                          \
            : "v"(ar[p][0][0]), "v"(ar[p][0][1]));                             \
        asm("v_cvt_pk_bf16_f32 %0, %1, %2" : "=v"(c1)                          \
            : "v"(ar[p][0][2]), "v"(ar[p][0][3]));                             \
        asm("v_cvt_pk_bf16_f32 %0, %1, %2" : "=v"(c2)                          \
            : "v"(ar[p][1][0]), "v"(ar[p][1][1]));                             \
        asm("v_cvt_pk_bf16_f32 %0, %1, %2" : "=v"(c3)                          \
            : "v"(ar[p][1][2]), "v"(ar[p][1][3]));                             \
        u32x4 pk = {c0, c1, c2, c3};                                           \
        *(u32x4*)(smem + (w * 32 + p * 8) * 128 + lane * 16) = pk;             \
      }                                                                        \
    } while (0)

  #define STAGE_B(k0)                                                          \
    do {                                                                       \
      _Pragma("unroll")                                                        \
      for (int p = 0; p < 4; ++p)                                              \
        async16(&W[(size_t)(bn * 128 + srow + p * 8) * K + (k0) + scolsw],     \
                smem + 16384 + (w * 32 + p * 8) * 128);                        \
    } while (0)

  LOADA(0);
  for (int k0 = 0; k0 < K; k0 += 64) {
    STAGE_B(k0);
    WRITEA();                       // consumes ar (tile k0)
    if (k0 + 64 < K) LOADA(k0 + 64);  // issue next A loads; retire next iter
    __syncthreads();                // drains async B (vmcnt) + A ds_writes
    #pragma unroll
    for (int ksub = 0; ksub < 4; ++ksub) {
      const int koff = ksub * 32 + hi * 16;   // byte offset in 128B row
      bf16x8 aA[2], bB[2];
      #pragma unroll
      for (int rb = 0; rb < 2; rb++) {
        int row = wr * 64 + rb * 32 + l32;
        aA[rb] = *(const bf16x8*)(smem + row * 128 + (koff ^ ((l32 & 7) << 4)));
      }
      #pragma unroll
      for (int cb = 0; cb < 2; cb++) {
        int row = wc * 64 + cb * 32 + l32;
        bB[cb] = *(const bf16x8*)(smem + 16384 + row * 128 +
                                  (koff ^ ((l32 & 7) << 4)));
      }
      #pragma unroll
      for (int rb = 0; rb < 2; rb++)
        #pragma unroll
        for (int cb = 0; cb < 2; cb++)
          acc[rb][cb] = mfma32(aA[rb], bB[cb], acc[rb][cb]);
    }
    __syncthreads();                // all waves done reading before overwrite
  }
  #undef LOADA
  #undef WRITEA
  #undef STAGE_B

  // ---- via-LDS epilogue (r11, verified): coalesced 16B stores -------------
  unsigned short* Lw = (unsigned short*)(smem + w * 9216);   // [64][72] u16
  if (mode0) {
    #pragma unroll
    for (int rb = 0; rb < 2; rb++)
      #pragma unroll
      for (int cb = 0; cb < 2; cb++)
        #pragma unroll
        for (int r = 0; r < 16; r++) {
          int ml = rb * 32 + (r & 3) + 8 * (r >> 2) + 4 * hi;
          int nl = cb * 32 + l32;
          Lw[ml * 72 + nl] = f2bf(acc[rb][cb][r] * oscale);
        }
  } else {
    #pragma unroll
    for (int rb = 0; rb < 2; rb++)
      #pragma unroll
      for (int cb = 0; cb < 2; cb++)
        #pragma unroll
        for (int r = 0; r < 16; r++) {
          int ml = rb * 32 + (r & 3) + 8 * (r >> 2) + 4 * hi;
          int nl = cb * 32 + l32;
          Lw[nl * 72 + ml] = f2bf(acc[rb][cb][r] * oscale);
        }
  }
  asm volatile("s_waitcnt lgkmcnt(0)" ::: "memory");

  const int rows0 = bm * 128 + wr * 64;
  const int cols0 = bn * 128 + wc * 64;
  #pragma unroll
  for (int c = 0; c < 8; c++) {
    int task = c * 64 + lane;
    int i0 = task >> 3;           // outer-dim local index
    int j0 = (task & 7) * 8;      // 8-elem chunk in inner dim
    u16x8 vv = *(const u16x8*)&Lw[i0 * 72 + j0];
    if (mode0) {
      int row = rows0 + i0, col = cols0 + j0;
      size_t idx = ((size_t)((row >> 11) * N_HEADS + (col >> 6)) * S_LEN +
                    (row & (S_LEN - 1))) * D_HEAD + (col & (D_HEAD - 1));
      *(u16x8*)&out[idx] = vv;
    } else {
      int col = cols0 + i0, row = rows0 + j0;
      size_t idx = ((size_t)((row >> 11) * N_HEADS + (col >> 6)) * D_HEAD +
                    (col & (D_HEAD - 1))) * S_LEN + (row & (S_LEN - 1));
      *(u16x8*)&out[idx] = vv;
    }
  }
}

// Final output GEMM: C[M,N] f32 = ax @ wo^T (round-11 structure, unchanged).
__global__ __launch_bounds__(256) void out_gemm(
    const unsigned short* __restrict__ A, const unsigned short* __restrict__ W,
    float* __restrict__ out, int M, int N, int K) {
  __shared__ __align__(16) unsigned short As[2][128 * 64];
  __shared__ __align__(16) unsigned short Bs[2][128 * 64];
  const int tid = threadIdx.x;
  const int lane = tid & 63;
  const int w = tid >> 6;
  const int wr = w >> 1, wc = w & 1;
  const int l32 = lane & 31, hi = lane >> 5;

  const int nwg = gridDim.x * gridDim.y;
  const int bid = blockIdx.y * gridDim.x + blockIdx.x;
  const int wg = (bid & 7) * (nwg >> 3) + (bid >> 3);
  const int bm = wg >> 3;
  const int bn = wg & 7;

  f32x16 acc[2][2];
  #pragma unroll
  for (int i = 0; i < 2; i++)
    #pragma unroll
    for (int j = 0; j < 2; j++)
      #pragma unroll
      for (int r = 0; r < 16; r++) acc[i][j][r] = 0.f;

  const int srow = w * 32 + (lane >> 3);
  const int scolsw = ((lane & 7) ^ (lane >> 3)) * 8;

  #define STAGE_G(b, k0)                                                       \
    do {                                                                       \
      _Pragma("unroll")                                                        \
      for (int p = 0; p < 4; ++p) {                                            \
        async16(&A[(size_t)(bm * 128 + srow + p * 8) * K + (k0) + scolsw],     \
                &As[b][(w * 32 + p * 8) * 64]);                                \
        async16(&W[(size_t)(bn * 128 + srow + p * 8) * K + (k0) + scolsw],     \
                &Bs[b][(w * 32 + p * 8) * 64]);                                \
      }                                                                        \
    } while (0)

  STAGE_G(0, 0);
  __syncthreads();

  int buf = 0;
  for (int k0 = 0; k0 < K; k0 += 64) {
    if (k0 + 64 < K) STAGE_G(buf ^ 1, k0 + 64);
    #pragma unroll
    for (int ksub = 0; ksub < 4; ++ksub) {
      const int koff = ksub * 32 + hi * 16;
      bf16x8 aA[2], bB[2];
      #pragma unroll
      for (int rb = 0; rb < 2; rb++) {
        int row = wr * 64 + rb * 32 + l32;
        aA[rb] = *(const bf16x8*)((const char*)As[buf] + row * 128 +
                                  (koff ^ ((l32 & 7) << 4)));
      }
      #pragma unroll
      for (int cb = 0; cb < 2; cb++) {
        int row = wc * 64 + cb * 32 + l32;
        bB[cb] = *(const bf16x8*)((const char*)Bs[buf] + row * 128 +
                                  (koff ^ ((l32 & 7) << 4)));
      }
      #pragma unroll
      for (int rb = 0; rb < 2; rb++)
        #pragma unroll
        for (int cb = 0; cb < 2; cb++)
          acc[rb][cb] = mfma32(aA[rb], bB[cb], acc[rb][cb]);
    }
    __syncthreads();
    buf ^= 1;
  }
  #undef STAGE_G

  #pragma unroll
  for (int rb = 0; rb < 2; rb++)
    #pragma unroll
    for (int cb = 0; cb < 2; cb++)
      #pragma unroll
      for (int r = 0; r < 16; r++) {
        int row = bm * 128 + wr * 64 + rb * 32 + (r & 3) + 8 * (r >> 2) + 4 * hi;
        int col = bn * 128 + wc * 64 + cb * 32 + l32;
        out[(size_t)row * N + col] = acc[rb][cb][r];
      }
}

// Flash attention: round-11 config (tree max/sum) — unchanged.
__global__ __launch_bounds__(512, 4) void attn_kernel(
    const unsigned short* __restrict__ qh, const unsigned short* __restrict__ kh,
    const unsigned short* __restrict__ vt, unsigned short* __restrict__ xout) {
  __shared__ __align__(16) char smem[66560];
  const int tid = threadIdx.x;
  const int lane = tid & 63;
  const int w = tid >> 6;          // 0..7
  const int l32 = lane & 31;
  const int hi = lane >> 5;

  const int bid = blockIdx.x;                    // nwg = 512
  const int wg = (bid & 7) * 64 + (bid >> 3);    // XCD-chunked remap
  const int bh = wg >> 3;                        // 8 q-blocks per head
  const int qb = (wg & 7) * 256 + w * 32;

  const char* Kb = (const char*)kh + (size_t)bh * S_LEN * D_HEAD * 2;
  const char* Vb = (const char*)vt + (size_t)bh * D_HEAD * S_LEN * 2;
  const unsigned short* Q = qh + (size_t)bh * S_LEN * D_HEAD;

  bf16x8 qf[4];
  #pragma unroll
  for (int ks = 0; ks < 4; ks++)
    qf[ks] = *(const bf16x8*)&Q[(qb + l32) * 64 + ks * 16 + hi * 8];

  f32x16 o0, o1;
  #pragma unroll
  for (int r = 0; r < 16; r++) { o0[r] = 0.f; o1[r] = 0.f; }
  float m2 = -1e30f;
  float lsum = 0.f;

  #define STAGE_K(dstb, t)                                                     \
    do {                                                                       \
      int loff = tid * 16;                                                     \
      int krow = loff >> 7;                                                    \
      async16(Kb + (size_t)(t) * 8192 + (loff ^ ((krow & 7) << 4)),            \
              smem + (dstb) * 8192 + w * 1024);                                \
    } while (0)
  #define STAGE_V(dstb, t)                                                     \
    do {                                                                       \
      int loff = tid * 16;                                                     \
      int d = loff >> 7;                                                       \
      int colb = loff & 127;                                                   \
      async16(Vb + (size_t)d * 4096 + (t) * 128 + (colb ^ ((d & 7) << 4)),     \
              smem + 24576 + (dstb) * 8192 + w * 1024);                        \
    } while (0)

  auto compute = [&](const char* Ks, const char* Vs) __attribute__((always_inline)) {
    f32x16 s0, s1;
    #pragma unroll
    for (int r = 0; r < 16; r++) { s0[r] = 0.f; s1[r] = 0.f; }

    __builtin_amdgcn_s_setprio(1);
    #pragma unroll
    for (int ks = 0; ks < 4; ks++) {
      int row = l32;
      bf16x8 ka = *(const bf16x8*)(Ks + ((row * 128 + ks * 32 + hi * 16) ^
                                         ((row & 7) << 4)));
      s0 = mfma32(ka, qf[ks], s0);
    }
    #pragma unroll
    for (int ks = 0; ks < 4; ks++) {
      int row = 32 + l32;
      bf16x8 ka = *(const bf16x8*)(Ks + ((row * 128 + ks * 32 + hi * 16) ^
                                         ((row & 7) << 4)));
      s1 = mfma32(ka, qf[ks], s1);
    }
    __builtin_amdgcn_s_setprio(0);

    // online softmax (log2 domain; Q pre-scaled), defer-max THR=8, tree max
    float m8[8];
    #pragma unroll
    for (int t = 0; t < 8; t++)
      m8[t] = fmaxf(fmaxf(s0[2 * t], s0[2 * t + 1]),
                    fmaxf(s1[2 * t], s1[2 * t + 1]));
    float mx = fmaxf(fmaxf(fmaxf(m8[0], m8[1]), fmaxf(m8[2], m8[3])),
                     fmaxf(fmaxf(m8[4], m8[5]), fmaxf(m8[6], m8[7])));
    mx = fmaxf(mx, __shfl_xor(mx, 32));
    if (__any(mx > m2 + 8.0f)) {
      float mn = fmaxf(m2, mx);
      float sc = __builtin_amdgcn_exp2f(m2 - mn);
      lsum *= sc;
      #pragma unroll
      for (int r = 0; r < 16; r++) { o0[r] *= sc; o1[r] *= sc; }
      m2 = mn;
    }
    #pragma unroll
    for (int r = 0; r < 16; r++) {
      s0[r] = __builtin_amdgcn_exp2f(s0[r] - m2);   // bounded by 2^8
      s1[r] = __builtin_amdgcn_exp2f(s1[r] - m2);
    }
    float p8[8];
    #pragma unroll
    for (int t = 0; t < 8; t++)
      p8[t] = (s0[2 * t] + s0[2 * t + 1]) + (s1[2 * t] + s1[2 * t + 1]);
    lsum += ((p8[0] + p8[1]) + (p8[2] + p8[3])) +
            ((p8[4] + p8[5]) + (p8[6] + p8[7]));

    unsigned c[8], e[8];
    #pragma unroll
    for (int t = 0; t < 8; t++) {
      asm("v_cvt_pk_bf16_f32 %0, %1, %2"
          : "=v"(c[t]) : "v"(s0[2 * t]), "v"(s0[2 * t + 1]));
      asm("v_cvt_pk_bf16_f32 %0, %1, %2"
          : "=v"(e[t]) : "v"(s1[2 * t]), "v"(s1[2 * t + 1]));
    }
    asm("v_permlane32_swap_b32 %0, %1" : "+v"(c[0]), "+v"(c[2]));
    asm("v_permlane32_swap_b32 %0, %1" : "+v"(c[1]), "+v"(c[3]));
    asm("v_permlane32_swap_b32 %0, %1" : "+v"(c[4]), "+v"(c[6]));
    asm("v_permlane32_swap_b32 %0, %1" : "+v"(c[5]), "+v"(c[7]));
    asm("v_permlane32_swap_b32 %0, %1" : "+v"(e[0]), "+v"(e[2]));
    asm("v_permlane32_swap_b32 %0, %1" : "+v"(e[1]), "+v"(e[3]));
    asm("v_permlane32_swap_b32 %0, %1" : "+v"(e[4]), "+v"(e[6]));
    asm("v_permlane32_swap_b32 %0, %1" : "+v"(e[5]), "+v"(e[7]));
    u32x4 t0 = {c[0], c[1], c[2], c[3]};
    u32x4 t1 = {c[4], c[5], c[6], c[7]};
    u32x4 t2 = {e[0], e[1], e[2], e[3]};
    u32x4 t3 = {e[4], e[5], e[6], e[7]};
    bf16x8 pa0 = __builtin_bit_cast(bf16x8, t0);
    bf16x8 pa1 = __builtin_bit_cast(bf16x8, t1);
    bf16x8 pa2 = __builtin_bit_cast(bf16x8, t2);
    bf16x8 pa3 = __builtin_bit_cast(bf16x8, t3);

    __builtin_amdgcn_s_setprio(1);
    {
      int row = l32;
      bf16x8 va0 = *(const bf16x8*)(Vs + ((row * 128 + 0 * 32 + hi * 16) ^ ((row & 7) << 4)));
      bf16x8 va1 = *(const bf16x8*)(Vs + ((row * 128 + 1 * 32 + hi * 16) ^ ((row & 7) << 4)));
      bf16x8 va2 = *(const bf16x8*)(Vs + ((row * 128 + 2 * 32 + hi * 16) ^ ((row & 7) << 4)));
      bf16x8 va3 = *(const bf16x8*)(Vs + ((row * 128 + 3 * 32 + hi * 16) ^ ((row & 7) << 4)));
      o0 = mfma32(va0, pa0, o0);
      o0 = mfma32(va1, pa1, o0);
      o0 = mfma32(va2, pa2, o0);
      o0 = mfma32(va3, pa3, o0);
    }
    {
      int row = 32 + l32;
      bf16x8 va0 = *(const bf16x8*)(Vs + ((row * 128 + 0 * 32 + hi * 16) ^ ((row & 7) << 4)));
      bf16x8 va1 = *(const bf16x8*)(Vs + ((row * 128 + 1 * 32 + hi * 16) ^ ((row & 7) << 4)));
      bf16x8 va2 = *(const bf16x8*)(Vs + ((row * 128 + 2 * 32 + hi * 16) ^ ((row & 7) << 4)));
      bf16x8 va3 = *(const bf16x8*)(Vs + ((row * 128 + 3 * 32 + hi * 16) ^ ((row & 7) << 4)));
      o1 = mfma32(va0, pa0, o1);
      o1 = mfma32(va1, pa1, o1);
      o1 = mfma32(va2, pa2, o1);
      o1 = mfma32(va3, pa3, o1);
    }
    __builtin_amdgcn_s_setprio(0);
  };

  // Prologue: K0, V0, K1 in flight — issue order PINNED (vmcnt counts on it).
  STAGE_K(0, 0);
  __builtin_amdgcn_sched_barrier(0);
  STAGE_V(0, 0);
  __builtin_amdgcn_sched_barrier(0);
  STAGE_K(1, 1);
  __builtin_amdgcn_sched_barrier(0);

  int kcur = 0, vcur = 0;
  for (int t = 0; t < S_LEN / 64 - 1; ++t) {    // t = 0..30
    asm volatile("s_waitcnt vmcnt(1)" ::: "memory");
    __builtin_amdgcn_s_barrier();
    __builtin_amdgcn_sched_barrier(0);
    int vnx = vcur ^ 1;
    STAGE_V(vnx, t + 1);
    __builtin_amdgcn_sched_barrier(0);
    if (t < S_LEN / 64 - 2) {
      int knx = kcur + 2; if (knx >= 3) knx -= 3;
      STAGE_K(knx, t + 2);
    }
    __builtin_amdgcn_sched_barrier(0);
    compute(smem + kcur * 8192, smem + 24576 + vcur * 8192);
    kcur = (kcur == 2) ? 0 : kcur + 1;
    vcur = vnx;
  }
  asm volatile("s_waitcnt vmcnt(0)" ::: "memory");
  __builtin_amdgcn_s_barrier();
  __builtin_amdgcn_sched_barrier(0);
  compute(smem + kcur * 8192, smem + 24576 + vcur * 8192);   // t = 31

  #undef STAGE_K
  #undef STAGE_V

  lsum += __shfl_xor(lsum, 32);
  float inv = 1.0f / lsum;

  __syncthreads();   // all waves done with K/V LDS before O reuse
  float* O = (float*)(smem) + w * (32 * 65);
  #pragma unroll
  for (int r = 0; r < 16; r++) {
    int d = (r & 3) + 8 * (r >> 2) + 4 * hi;
    O[l32 * 65 + d] = o0[r] * inv;
    O[l32 * 65 + 32 + d] = o1[r] * inv;
  }
  __syncthreads();
  const int qr = lane >> 1;
  const int coff = (lane & 1) * 32;
  const int b = bh >> 4, h = bh & 15;
  unsigned short* dst =
      &xout[((size_t)(b * S_LEN) + qb + qr) * D_EMBD + h * 64 + coff];
  #pragma unroll
  for (int t = 0; t < 4; t++) {
    u16x8 rr;
    #pragma unroll
    for (int j = 0; j < 8; j++)
      rr[j] = f2bf(O[qr * 65 + coff + t * 8 + j]);
    *(u16x8*)(dst + t * 8) = rr;
  }
}

extern "C" void kernel_launch(void* const* d_in, const int* in_sizes, int n_in,
                              void* d_out, int out_size, void* d_ws, size_t ws_size,
                              hipStream_t stream) {
  const float* q   = (const float*)d_in[0];
  const float* k   = (const float*)d_in[1];
  const float* v   = (const float*)d_in[2];
  const float* wqf = (const float*)d_in[3];
  const float* wkf = (const float*)d_in[4];
  const float* wvf = (const float*)d_in[5];
  const float* wof = (const float*)d_in[6];

  char* ws = (char*)d_ws;
  unsigned short* qh = (unsigned short*)(ws + (16u << 20));        // 16 MB
  unsigned short* kh = (unsigned short*)(ws + (32u << 20));        // 16 MB
  unsigned short* vt = (unsigned short*)(ws + (48u << 20));        // 16 MB
  unsigned short* ax = (unsigned short*)(ws + (64u << 20));        // 16 MB
  unsigned short* wq = (unsigned short*)(ws + (80u << 20));        // 2 MB: wq..wo contiguous
  unsigned short* wo = wq + (3u << 20);

  const float QSCALE = 0.125f * 1.4426950408889634f;

  cast_w4_kernel<<<2048, 256, 0, stream>>>(wqf, wkf, wvf, wof, wq);

  // Merged Q/K/V projections (z selects tensor; qh/kh/vt contiguous @16MB).
  proj_gemm<<<dim3(8, 64, 3), 256, 0, stream>>>(q, k, v, wq, qh, QSCALE);

  attn_kernel<<<512, 512, 0, stream>>>(qh, kh, vt, ax);

  out_gemm<<<dim3(8, 64), 256, 0, stream>>>(ax, wo, (float*)d_out,
                                            M_TOT, D_EMBD, D_EMBD);
}

// Round 14
// 195.200 us; speedup vs baseline: 1.0657x; 1.0636x over previous
//
#include <hip/hip_runtime.h>
#include <stdint.h>

#define S_LEN 2048
#define D_EMBD 1024
#define N_HEADS 16
#define D_HEAD 64
#define B_SZ 4
#define M_TOT (B_SZ * S_LEN)   // 8192

typedef __bf16 bf16x8 __attribute__((ext_vector_type(8)));
typedef float f32x4 __attribute__((ext_vector_type(4)));
typedef float f32x16 __attribute__((ext_vector_type(16)));
typedef unsigned short u16x8 __attribute__((ext_vector_type(8)));
typedef unsigned int u32x4 __attribute__((ext_vector_type(4)));

__device__ __forceinline__ unsigned short f2bf(float f) {
  unsigned u = __builtin_bit_cast(unsigned, f);
  u += 0x7fffu + ((u >> 16) & 1u);
  return (unsigned short)(u >> 16);
}

__device__ __forceinline__ void async16(const void* g, void* l) {
  __builtin_amdgcn_global_load_lds(
      (const __attribute__((address_space(1))) void*)(uintptr_t)g,
      (__attribute__((address_space(3))) void*)(unsigned)(uintptr_t)l,
      16, 0, 0);
}

__device__ __forceinline__ f32x16 mfma32(bf16x8 a, bf16x8 b, f32x16 c) {
  return __builtin_amdgcn_mfma_f32_32x32x16_bf16(a, b, c, 0, 0, 0);
}

// All 4 weight matrices cast in one launch; dst buffers are contiguous.
__global__ __launch_bounds__(256) void cast_w4_kernel(
    const float* __restrict__ w0, const float* __restrict__ w1,
    const float* __restrict__ w2, const float* __restrict__ w3,
    unsigned short* __restrict__ out) {
  int i = blockIdx.x * 256 + threadIdx.x;        // 4 * 131072 threads
  int seg = i >> 17;
  int off = i & ((1 << 17) - 1);
  const float* src = (seg == 0) ? w0 : (seg == 1) ? w1 : (seg == 2) ? w2 : w3;
  size_t sb = (size_t)off * 8;
  float4 a = *(const float4*)(src + sb);
  float4 b = *(const float4*)(src + sb + 4);
  u16x8 r;
  r[0] = f2bf(a.x); r[1] = f2bf(a.y); r[2] = f2bf(a.z); r[3] = f2bf(a.w);
  r[4] = f2bf(b.x); r[5] = f2bf(b.y); r[6] = f2bf(b.z); r[7] = f2bf(b.w);
  *(u16x8*)(out + (size_t)i * 8) = r;
}

// Merged Q/K/V projection GEMM: grid (8, 64, 3); z selects {A, W, out, mode}.
// "1.5-buffer": B double-buffered async16 (prefetch before compute = full
// compute-phase cover, r11-proven); A single-buffered LDS with register
// prefetch one full iteration ahead (WRITEA between two barriers after
// compute — only the fast ds_write burst is exposed). LDS 48KB -> 3 blocks/CU
// (r11's 64KB allowed only 2).
__global__ __launch_bounds__(256) void proj_gemm(
    const float* __restrict__ Aq, const float* __restrict__ Ak,
    const float* __restrict__ Av, const unsigned short* __restrict__ Wbase,
    unsigned short* __restrict__ Obase, float qscale) {
  constexpr int K = 1024;
  __shared__ __align__(16) char smem[49152];
  // A-lds @0 (16KB), Bs[0] @16384, Bs[1] @32768; epilogue wave tile @ w*9216
  const int tid = threadIdx.x;
  const int lane = tid & 63;
  const int w = tid >> 6;
  const int wr = w >> 1, wc = w & 1;
  const int l32 = lane & 31, hi = lane >> 5;

  const int z = blockIdx.z;
  const float* A32 = (z == 0) ? Aq : (z == 1) ? Ak : Av;
  const unsigned short* W = Wbase + ((size_t)z << 20);
  unsigned short* out = Obase + ((size_t)z << 23);
  const float oscale = (z == 0) ? qscale : 1.0f;
  const bool mode0 = (z < 2);

  const int nwg = gridDim.x * gridDim.y;   // 512 per slice
  const int bid = blockIdx.y * gridDim.x + blockIdx.x;
  const int wg = (bid & 7) * (nwg >> 3) + (bid >> 3);
  const int bm = wg >> 3;
  const int bn = wg & 7;

  f32x16 acc[2][2];
  #pragma unroll
  for (int i = 0; i < 2; i++)
    #pragma unroll
    for (int j = 0; j < 2; j++)
      #pragma unroll
      for (int r = 0; r < 16; r++) acc[i][j][r] = 0.f;

  const int srow = w * 32 + (lane >> 3);
  const int scolsw = ((lane & 7) ^ (lane >> 3)) * 8;   // elems

  f32x4 ar[4][2];   // fp32 A staging regs (one iteration ahead)

  #define LOADA(k0)                                                            \
    do {                                                                       \
      _Pragma("unroll")                                                        \
      for (int p = 0; p < 4; ++p) {                                            \
        const float* srcp =                                                    \
            &A32[(size_t)(bm * 128 + srow + p * 8) * K + (k0) + scolsw];       \
        ar[p][0] = *(const f32x4*)srcp;                                        \
        ar[p][1] = *(const f32x4*)(srcp + 4);                                  \
      }                                                                        \
    } while (0)

  #define WRITEA()                                                             \
    do {                                                                       \
      _Pragma("unroll")                                                        \
      for (int p = 0; p < 4; ++p) {                                            \
        unsigned c0, c1, c2, c3;                                               \
        asm("v_cvt_pk_bf16_f32 %0, %1, %2" : "=v"(c0)                          \
            : "v"(ar[p][0][0]), "v"(ar[p][0][1]));                             \
        asm("v_cvt_pk_bf16_f32 %0, %1, %2" : "=v"(c1)                          \
            : "v"(ar[p][0][2]), "v"(ar[p][0][3]));                             \
        asm("v_cvt_pk_bf16_f32 %0, %1, %2" : "=v"(c2)                          \
            : "v"(ar[p][1][0]), "v"(ar[p][1][1]));                             \
        asm("v_cvt_pk_bf16_f32 %0, %1, %2" : "=v"(c3)                          \
            : "v"(ar[p][1][2]), "v"(ar[p][1][3]));                             \
        u32x4 pk = {c0, c1, c2, c3};                                           \
        *(u32x4*)(smem + (w * 32 + p * 8) * 128 + lane * 16) = pk;             \
      }                                                                        \
    } while (0)

  #define STAGE_B(b, k0)                                                       \
    do {                                                                       \
      _Pragma("unroll")                                                        \
      for (int p = 0; p < 4; ++p)                                              \
        async16(&W[(size_t)(bn * 128 + srow + p * 8) * K + (k0) + scolsw],     \
                smem + 16384 + (b) * 16384 + (w * 32 + p * 8) * 128);          \
    } while (0)

  // Prologue: A(0) -> LDS, B(0) async, A(1) -> regs.
  LOADA(0);
  STAGE_B(0, 0);
  WRITEA();
  LOADA(64);
  __syncthreads();   // drains B(0) async + A(0) ds_writes

  int buf = 0;
  for (int k0 = 0; k0 < K; k0 += 64) {
    const bool more = (k0 + 64 < K);
    if (more) STAGE_B(buf ^ 1, k0 + 64);   // full compute-phase cover
    #pragma unroll
    for (int ksub = 0; ksub < 4; ++ksub) {
      const int koff = ksub * 32 + hi * 16;   // byte offset in 128B row
      bf16x8 aA[2], bB[2];
      #pragma unroll
      for (int rb = 0; rb < 2; rb++) {
        int row = wr * 64 + rb * 32 + l32;
        aA[rb] = *(const bf16x8*)(smem + row * 128 + (koff ^ ((l32 & 7) << 4)));
      }
      #pragma unroll
      for (int cb = 0; cb < 2; cb++) {
        int row = wc * 64 + cb * 32 + l32;
        bB[cb] = *(const bf16x8*)(smem + 16384 + buf * 16384 + row * 128 +
                                  (koff ^ ((l32 & 7) << 4)));
      }
      #pragma unroll
      for (int rb = 0; rb < 2; rb++)
        #pragma unroll
        for (int cb = 0; cb < 2; cb++)
          acc[rb][cb] = mfma32(aA[rb], bB[cb], acc[rb][cb]);
    }
    __syncthreads();               // all waves done reading A-lds & B[buf]
    if (more) {
      WRITEA();                    // A(k0+64): regs loaded a full iter ago
      if (k0 + 128 < K) LOADA(k0 + 128);
    }
    __syncthreads();               // A writes visible; B(t+1) had long cover
    buf ^= 1;
  }
  #undef LOADA
  #undef WRITEA
  #undef STAGE_B

  // ---- via-LDS epilogue (r11, verified): coalesced 16B stores -------------
  unsigned short* Lw = (unsigned short*)(smem + w * 9216);   // [64][72] u16
  if (mode0) {
    #pragma unroll
    for (int rb = 0; rb < 2; rb++)
      #pragma unroll
      for (int cb = 0; cb < 2; cb++)
        #pragma unroll
        for (int r = 0; r < 16; r++) {
          int ml = rb * 32 + (r & 3) + 8 * (r >> 2) + 4 * hi;
          int nl = cb * 32 + l32;
          Lw[ml * 72 + nl] = f2bf(acc[rb][cb][r] * oscale);
        }
  } else {
    #pragma unroll
    for (int rb = 0; rb < 2; rb++)
      #pragma unroll
      for (int cb = 0; cb < 2; cb++)
        #pragma unroll
        for (int r = 0; r < 16; r++) {
          int ml = rb * 32 + (r & 3) + 8 * (r >> 2) + 4 * hi;
          int nl = cb * 32 + l32;
          Lw[nl * 72 + ml] = f2bf(acc[rb][cb][r] * oscale);
        }
  }
  asm volatile("s_waitcnt lgkmcnt(0)" ::: "memory");

  const int rows0 = bm * 128 + wr * 64;
  const int cols0 = bn * 128 + wc * 64;
  #pragma unroll
  for (int c = 0; c < 8; c++) {
    int task = c * 64 + lane;
    int i0 = task >> 3;           // outer-dim local index
    int j0 = (task & 7) * 8;      // 8-elem chunk in inner dim
    u16x8 vv = *(const u16x8*)&Lw[i0 * 72 + j0];
    if (mode0) {
      int row = rows0 + i0, col = cols0 + j0;
      size_t idx = ((size_t)((row >> 11) * N_HEADS + (col >> 6)) * S_LEN +
                    (row & (S_LEN - 1))) * D_HEAD + (col & (D_HEAD - 1));
      *(u16x8*)&out[idx] = vv;
    } else {
      int col = cols0 + i0, row = rows0 + j0;
      size_t idx = ((size_t)((row >> 11) * N_HEADS + (col >> 6)) * D_HEAD +
                    (col & (D_HEAD - 1))) * S_LEN + (row & (S_LEN - 1));
      *(u16x8*)&out[idx] = vv;
    }
  }
}

// Final output GEMM: C[M,N] f32 = ax @ wo^T (round-11 structure, unchanged).
__global__ __launch_bounds__(256) void out_gemm(
    const unsigned short* __restrict__ A, const unsigned short* __restrict__ W,
    float* __restrict__ out, int M, int N, int K) {
  __shared__ __align__(16) unsigned short As[2][128 * 64];
  __shared__ __align__(16) unsigned short Bs[2][128 * 64];
  const int tid = threadIdx.x;
  const int lane = tid & 63;
  const int w = tid >> 6;
  const int wr = w >> 1, wc = w & 1;
  const int l32 = lane & 31, hi = lane >> 5;

  const int nwg = gridDim.x * gridDim.y;
  const int bid = blockIdx.y * gridDim.x + blockIdx.x;
  const int wg = (bid & 7) * (nwg >> 3) + (bid >> 3);
  const int bm = wg >> 3;
  const int bn = wg & 7;

  f32x16 acc[2][2];
  #pragma unroll
  for (int i = 0; i < 2; i++)
    #pragma unroll
    for (int j = 0; j < 2; j++)
      #pragma unroll
      for (int r = 0; r < 16; r++) acc[i][j][r] = 0.f;

  const int srow = w * 32 + (lane >> 3);
  const int scolsw = ((lane & 7) ^ (lane >> 3)) * 8;

  #define STAGE_G(b, k0)                                                       \
    do {                                                                       \
      _Pragma("unroll")                                                        \
      for (int p = 0; p < 4; ++p) {                                            \
        async16(&A[(size_t)(bm * 128 + srow + p * 8) * K + (k0) + scolsw],     \
                &As[b][(w * 32 + p * 8) * 64]);                                \
        async16(&W[(size_t)(bn * 128 + srow + p * 8) * K + (k0) + scolsw],     \
                &Bs[b][(w * 32 + p * 8) * 64]);                                \
      }                                                                        \
    } while (0)

  STAGE_G(0, 0);
  __syncthreads();

  int buf = 0;
  for (int k0 = 0; k0 < K; k0 += 64) {
    if (k0 + 64 < K) STAGE_G(buf ^ 1, k0 + 64);
    #pragma unroll
    for (int ksub = 0; ksub < 4; ++ksub) {
      const int koff = ksub * 32 + hi * 16;
      bf16x8 aA[2], bB[2];
      #pragma unroll
      for (int rb = 0; rb < 2; rb++) {
        int row = wr * 64 + rb * 32 + l32;
        aA[rb] = *(const bf16x8*)((const char*)As[buf] + row * 128 +
                                  (koff ^ ((l32 & 7) << 4)));
      }
      #pragma unroll
      for (int cb = 0; cb < 2; cb++) {
        int row = wc * 64 + cb * 32 + l32;
        bB[cb] = *(const bf16x8*)((const char*)Bs[buf] + row * 128 +
                                  (koff ^ ((l32 & 7) << 4)));
      }
      #pragma unroll
      for (int rb = 0; rb < 2; rb++)
        #pragma unroll
        for (int cb = 0; cb < 2; cb++)
          acc[rb][cb] = mfma32(aA[rb], bB[cb], acc[rb][cb]);
    }
    __syncthreads();
    buf ^= 1;
  }
  #undef STAGE_G

  #pragma unroll
  for (int rb = 0; rb < 2; rb++)
    #pragma unroll
    for (int cb = 0; cb < 2; cb++)
      #pragma unroll
      for (int r = 0; r < 16; r++) {
        int row = bm * 128 + wr * 64 + rb * 32 + (r & 3) + 8 * (r >> 2) + 4 * hi;
        int col = bn * 128 + wc * 64 + cb * 32 + l32;
        out[(size_t)row * N + col] = acc[rb][cb][r];
      }
}

// Flash attention: round-11 config (tree max/sum) — unchanged.
__global__ __launch_bounds__(512, 4) void attn_kernel(
    const unsigned short* __restrict__ qh, const unsigned short* __restrict__ kh,
    const unsigned short* __restrict__ vt, unsigned short* __restrict__ xout) {
  __shared__ __align__(16) char smem[66560];
  const int tid = threadIdx.x;
  const int lane = tid & 63;
  const int w = tid >> 6;          // 0..7
  const int l32 = lane & 31;
  const int hi = lane >> 5;

  const int bid = blockIdx.x;                    // nwg = 512
  const int wg = (bid & 7) * 64 + (bid >> 3);    // XCD-chunked remap
  const int bh = wg >> 3;                        // 8 q-blocks per head
  const int qb = (wg & 7) * 256 + w * 32;

  const char* Kb = (const char*)kh + (size_t)bh * S_LEN * D_HEAD * 2;
  const char* Vb = (const char*)vt + (size_t)bh * D_HEAD * S_LEN * 2;
  const unsigned short* Q = qh + (size_t)bh * S_LEN * D_HEAD;

  bf16x8 qf[4];
  #pragma unroll
  for (int ks = 0; ks < 4; ks++)
    qf[ks] = *(const bf16x8*)&Q[(qb + l32) * 64 + ks * 16 + hi * 8];

  f32x16 o0, o1;
  #pragma unroll
  for (int r = 0; r < 16; r++) { o0[r] = 0.f; o1[r] = 0.f; }
  float m2 = -1e30f;
  float lsum = 0.f;

  #define STAGE_K(dstb, t)                                                     \
    do {                                                                       \
      int loff = tid * 16;                                                     \
      int krow = loff >> 7;                                                    \
      async16(Kb + (size_t)(t) * 8192 + (loff ^ ((krow & 7) << 4)),            \
              smem + (dstb) * 8192 + w * 1024);                                \
    } while (0)
  #define STAGE_V(dstb, t)                                                     \
    do {                                                                       \
      int loff = tid * 16;                                                     \
      int d = loff >> 7;                                                       \
      int colb = loff & 127;                                                   \
      async16(Vb + (size_t)d * 4096 + (t) * 128 + (colb ^ ((d & 7) << 4)),     \
              smem + 24576 + (dstb) * 8192 + w * 1024);                        \
    } while (0)

  auto compute = [&](const char* Ks, const char* Vs) __attribute__((always_inline)) {
    f32x16 s0, s1;
    #pragma unroll
    for (int r = 0; r < 16; r++) { s0[r] = 0.f; s1[r] = 0.f; }

    __builtin_amdgcn_s_setprio(1);
    #pragma unroll
    for (int ks = 0; ks < 4; ks++) {
      int row = l32;
      bf16x8 ka = *(const bf16x8*)(Ks + ((row * 128 + ks * 32 + hi * 16) ^
                                         ((row & 7) << 4)));
      s0 = mfma32(ka, qf[ks], s0);
    }
    #pragma unroll
    for (int ks = 0; ks < 4; ks++) {
      int row = 32 + l32;
      bf16x8 ka = *(const bf16x8*)(Ks + ((row * 128 + ks * 32 + hi * 16) ^
                                         ((row & 7) << 4)));
      s1 = mfma32(ka, qf[ks], s1);
    }
    __builtin_amdgcn_s_setprio(0);

    // online softmax (log2 domain; Q pre-scaled), defer-max THR=8, tree max
    float m8[8];
    #pragma unroll
    for (int t = 0; t < 8; t++)
      m8[t] = fmaxf(fmaxf(s0[2 * t], s0[2 * t + 1]),
                    fmaxf(s1[2 * t], s1[2 * t + 1]));
    float mx = fmaxf(fmaxf(fmaxf(m8[0], m8[1]), fmaxf(m8[2], m8[3])),
                     fmaxf(fmaxf(m8[4], m8[5]), fmaxf(m8[6], m8[7])));
    mx = fmaxf(mx, __shfl_xor(mx, 32));
    if (__any(mx > m2 + 8.0f)) {
      float mn = fmaxf(m2, mx);
      float sc = __builtin_amdgcn_exp2f(m2 - mn);
      lsum *= sc;
      #pragma unroll
      for (int r = 0; r < 16; r++) { o0[r] *= sc; o1[r] *= sc; }
      m2 = mn;
    }
    #pragma unroll
    for (int r = 0; r < 16; r++) {
      s0[r] = __builtin_amdgcn_exp2f(s0[r] - m2);   // bounded by 2^8
      s1[r] = __builtin_amdgcn_exp2f(s1[r] - m2);
    }
    float p8[8];
    #pragma unroll
    for (int t = 0; t < 8; t++)
      p8[t] = (s0[2 * t] + s0[2 * t + 1]) + (s1[2 * t] + s1[2 * t + 1]);
    lsum += ((p8[0] + p8[1]) + (p8[2] + p8[3])) +
            ((p8[4] + p8[5]) + (p8[6] + p8[7]));

    unsigned c[8], e[8];
    #pragma unroll
    for (int t = 0; t < 8; t++) {
      asm("v_cvt_pk_bf16_f32 %0, %1, %2"
          : "=v"(c[t]) : "v"(s0[2 * t]), "v"(s0[2 * t + 1]));
      asm("v_cvt_pk_bf16_f32 %0, %1, %2"
          : "=v"(e[t]) : "v"(s1[2 * t]), "v"(s1[2 * t + 1]));
    }
    asm("v_permlane32_swap_b32 %0, %1" : "+v"(c[0]), "+v"(c[2]));
    asm("v_permlane32_swap_b32 %0, %1" : "+v"(c[1]), "+v"(c[3]));
    asm("v_permlane32_swap_b32 %0, %1" : "+v"(c[4]), "+v"(c[6]));
    asm("v_permlane32_swap_b32 %0, %1" : "+v"(c[5]), "+v"(c[7]));
    asm("v_permlane32_swap_b32 %0, %1" : "+v"(e[0]), "+v"(e[2]));
    asm("v_permlane32_swap_b32 %0, %1" : "+v"(e[1]), "+v"(e[3]));
    asm("v_permlane32_swap_b32 %0, %1" : "+v"(e[4]), "+v"(e[6]));
    asm("v_permlane32_swap_b32 %0, %1" : "+v"(e[5]), "+v"(e[7]));
    u32x4 t0 = {c[0], c[1], c[2], c[3]};
    u32x4 t1 = {c[4], c[5], c[6], c[7]};
    u32x4 t2 = {e[0], e[1], e[2], e[3]};
    u32x4 t3 = {e[4], e[5], e[6], e[7]};
    bf16x8 pa0 = __builtin_bit_cast(bf16x8, t0);
    bf16x8 pa1 = __builtin_bit_cast(bf16x8, t1);
    bf16x8 pa2 = __builtin_bit_cast(bf16x8, t2);
    bf16x8 pa3 = __builtin_bit_cast(bf16x8, t3);

    __builtin_amdgcn_s_setprio(1);
    {
      int row = l32;
      bf16x8 va0 = *(const bf16x8*)(Vs + ((row * 128 + 0 * 32 + hi * 16) ^ ((row & 7) << 4)));
      bf16x8 va1 = *(const bf16x8*)(Vs + ((row * 128 + 1 * 32 + hi * 16) ^ ((row & 7) << 4)));
      bf16x8 va2 = *(const bf16x8*)(Vs + ((row * 128 + 2 * 32 + hi * 16) ^ ((row & 7) << 4)));
      bf16x8 va3 = *(const bf16x8*)(Vs + ((row * 128 + 3 * 32 + hi * 16) ^ ((row & 7) << 4)));
      o0 = mfma32(va0, pa0, o0);
      o0 = mfma32(va1, pa1, o0);
      o0 = mfma32(va2, pa2, o0);
      o0 = mfma32(va3, pa3, o0);
    }
    {
      int row = 32 + l32;
      bf16x8 va0 = *(const bf16x8*)(Vs + ((row * 128 + 0 * 32 + hi * 16) ^ ((row & 7) << 4)));
      bf16x8 va1 = *(const bf16x8*)(Vs + ((row * 128 + 1 * 32 + hi * 16) ^ ((row & 7) << 4)));
      bf16x8 va2 = *(const bf16x8*)(Vs + ((row * 128 + 2 * 32 + hi * 16) ^ ((row & 7) << 4)));
      bf16x8 va3 = *(const bf16x8*)(Vs + ((row * 128 + 3 * 32 + hi * 16) ^ ((row & 7) << 4)));
      o1 = mfma32(va0, pa0, o1);
      o1 = mfma32(va1, pa1, o1);
      o1 = mfma32(va2, pa2, o1);
      o1 = mfma32(va3, pa3, o1);
    }
    __builtin_amdgcn_s_setprio(0);
  };

  // Prologue: K0, V0, K1 in flight — issue order PINNED (vmcnt counts on it).
  STAGE_K(0, 0);
  __builtin_amdgcn_sched_barrier(0);
  STAGE_V(0, 0);
  __builtin_amdgcn_sched_barrier(0);
  STAGE_K(1, 1);
  __builtin_amdgcn_sched_barrier(0);

  int kcur = 0, vcur = 0;
  for (int t = 0; t < S_LEN / 64 - 1; ++t) {    // t = 0..30
    asm volatile("s_waitcnt vmcnt(1)" ::: "memory");
    __builtin_amdgcn_s_barrier();
    __builtin_amdgcn_sched_barrier(0);
    int vnx = vcur ^ 1;
    STAGE_V(vnx, t + 1);
    __builtin_amdgcn_sched_barrier(0);
    if (t < S_LEN / 64 - 2) {
      int knx = kcur + 2; if (knx >= 3) knx -= 3;
      STAGE_K(knx, t + 2);
    }
    __builtin_amdgcn_sched_barrier(0);
    compute(smem + kcur * 8192, smem + 24576 + vcur * 8192);
    kcur = (kcur == 2) ? 0 : kcur + 1;
    vcur = vnx;
  }
  asm volatile("s_waitcnt vmcnt(0)" ::: "memory");
  __builtin_amdgcn_s_barrier();
  __builtin_amdgcn_sched_barrier(0);
  compute(smem + kcur * 8192, smem + 24576 + vcur * 8192);   // t = 31

  #undef STAGE_K
  #undef STAGE_V

  lsum += __shfl_xor(lsum, 32);
  float inv = 1.0f / lsum;

  __syncthreads();   // all waves done with K/V LDS before O reuse
  float* O = (float*)(smem) + w * (32 * 65);
  #pragma unroll
  for (int r = 0; r < 16; r++) {
    int d = (r & 3) + 8 * (r >> 2) + 4 * hi;
    O[l32 * 65 + d] = o0[r] * inv;
    O[l32 * 65 + 32 + d] = o1[r] * inv;
  }
  __syncthreads();
  const int qr = lane >> 1;
  const int coff = (lane & 1) * 32;
  const int b = bh >> 4, h = bh & 15;
  unsigned short* dst =
      &xout[((size_t)(b * S_LEN) + qb + qr) * D_EMBD + h * 64 + coff];
  #pragma unroll
  for (int t = 0; t < 4; t++) {
    u16x8 rr;
    #pragma unroll
    for (int j = 0; j < 8; j++)
      rr[j] = f2bf(O[qr * 65 + coff + t * 8 + j]);
    *(u16x8*)(dst + t * 8) = rr;
  }
}

extern "C" void kernel_launch(void* const* d_in, const int* in_sizes, int n_in,
                              void* d_out, int out_size, void* d_ws, size_t ws_size,
                              hipStream_t stream) {
  const float* q   = (const float*)d_in[0];
  const float* k   = (const float*)d_in[1];
  const float* v   = (const float*)d_in[2];
  const float* wqf = (const float*)d_in[3];
  const float* wkf = (const float*)d_in[4];
  const float* wvf = (const float*)d_in[5];
  const float* wof = (const float*)d_in[6];

  char* ws = (char*)d_ws;
  unsigned short* qh = (unsigned short*)(ws + (16u << 20));        // 16 MB
  unsigned short* kh = (unsigned short*)(ws + (32u << 20));        // 16 MB
  unsigned short* vt = (unsigned short*)(ws + (48u << 20));        // 16 MB
  unsigned short* ax = (unsigned short*)(ws + (64u << 20));        // 16 MB
  unsigned short* wq = (unsigned short*)(ws + (80u << 20));        // 2 MB: wq..wo contiguous
  unsigned short* wo = wq + (3u << 20);

  const float QSCALE = 0.125f * 1.4426950408889634f;

  cast_w4_kernel<<<2048, 256, 0, stream>>>(wqf, wkf, wvf, wof, wq);

  // Merged Q/K/V projections (z selects tensor; qh/kh/vt contiguous @16MB).
  proj_gemm<<<dim3(8, 64, 3), 256, 0, stream>>>(q, k, v, wq, qh, QSCALE);

  attn_kernel<<<512, 512, 0, stream>>>(qh, kh, vt, ax);

  out_gemm<<<dim3(8, 64), 256, 0, stream>>>(ax, wo, (float*)d_out,
                                            M_TOT, D_EMBD, D_EMBD);
}